// Round 14
// baseline (50.671 us; speedup 1.0000x reference)
//
#include <hip/hip_runtime.h>
#include <cstdint>

#define B_    2048
#define T_    2048
#define TD    7
#define CSTR  164        // dwords per chunk region: 160 data + 4 pad (bank-free, GLL-aligned)
#define IDENT 0x4688u    // identity map: 0|1<<3|2<<6|3<<9|4<<12

// compose packed 5-slot maps: r[j] = f[g[j]]
__device__ __forceinline__ uint32_t mcompose(uint32_t f, uint32_t g) {
    uint32_t r = 0;
#pragma unroll
    for (int j = 0; j < 5; ++j) {
        uint32_t gj = (g >> (3 * j)) & 7u;
        r |= ((f >> (3 * gj)) & 7u) << (3 * j);
    }
    return r;
}

template<bool P>
__device__ __forceinline__ void hstep(const float* w, int base, bool pred,
                                      float (&dp)[5], const float (&tr)[5][5]) {
    float nd[5];
#pragma unroll
    for (int j = 0; j < 5; ++j) {
        float v = fmaxf(fmaxf(fmaxf(fmaxf(dp[0] + tr[0][j], dp[1] + tr[1][j]),
                                    dp[2] + tr[2][j]), dp[3] + tr[3][j]),
                        dp[4] + tr[4][j]);
        nd[j] = v + w[base + j];
    }
#pragma unroll
    for (int j = 0; j < 5; ++j) dp[j] = (P && !pred) ? dp[j] : nd[j];
}

// live step: mantissa-embedded argmax; no in-loop rho (composed post-loop)
template<bool SEL>
__device__ __forceinline__ uint32_t lstep(const float* w, int base, bool mm,
                                          float (&dp)[5], const float (&tr)[5][5]) {
    float nd[5]; uint32_t pk = 0;
#pragma unroll
    for (int j = 0; j < 5; ++j) {
        float s[5];
#pragma unroll
        for (int i = 0; i < 5; ++i) {
            float f = dp[i] + tr[i][j];
            s[i] = __uint_as_float((__float_as_uint(f) & ~7u) | (uint32_t)(7 - i)); // v_and_or_b32
        }
        float m = fmaxf(fmaxf(fmaxf(fmaxf(s[0], s[1]), s[2]), s[3]), s[4]);  // 2x v_max3
        int a = 7 - (int)(__float_as_uint(m) & 7u);
        float v = m + w[base + j];
        if (SEL) { a = mm ? a : j; nd[j] = mm ? v : dp[j]; }
        else     { nd[j] = v; }
        pk |= ((uint32_t)a) << (3 * j);
    }
#pragma unroll
    for (int j = 0; j < 5; ++j) dp[j] = nd[j];
    return pk;
}

__global__ __launch_bounds__(64) void k_all(
    const float* __restrict__ x, const int* __restrict__ mask,
    const float* __restrict__ tf, float* __restrict__ out)
{
    __shared__ __align__(16) float xs[64 * CSTR];   // 41984 B -> 3 blocks/CU
    const int b = blockIdx.x, c = threadIdx.x;      // c = chunk (L=32), 64 chunks

    const float* xrow = x + (size_t)b * (T_ * 5);
    const int*   gi   = mask + (size_t)b * T_;

    // ---- async DMA stage: 41 x global_load_lds dwordx4, pre-shifted source ----
    // LDS dword A = 256q + 4l; chunk cq = (A/4)/41; data dword = 160cq + 4off4
#pragma unroll
    for (int q = 0; q < 41; ++q) {
        uint32_t v    = 64u * (uint32_t)q + (uint32_t)c;
        uint32_t cq   = (v * 3198u) >> 17;            // v/41, exact in range
        uint32_t off4 = v - 41u * cq;                 // 0..40 (40 = pad block)
        uint32_t srcd = (off4 >= 40u) ? 0u : (160u * cq + 4u * off4);
        __builtin_amdgcn_global_load_lds(
            (const __attribute__((address_space(1))) uint32_t*)(xrow + srcd),
            (__attribute__((address_space(3))) uint32_t*)(xs + 256 * q),
            16, 0, 0);
    }

    // ---- mask: 32 coalesced loads (in flight with the DMA) ----
    int mv[32];
#pragma unroll
    for (int q = 0; q < 32; ++q) mv[q] = gi[c + 64 * q];

    float tr[5][5], ts[5], te[5];
#pragma unroll
    for (int i = 0; i < 5; ++i)
#pragma unroll
        for (int j = 0; j < 5; ++j) tr[i][j] = tf[i * TD + j];
#pragma unroll
    for (int j = 0; j < 5; ++j) ts[j] = tf[5 * TD + j];
#pragma unroll
    for (int j = 0; j < 5; ++j) te[j] = tf[j * TD + 6];

    // ballot-pack mask bits: lane cc gets 32 bits of chunk cc
    uint32_t mb = 0;
#pragma unroll
    for (int q = 0; q < 32; ++q) {
        unsigned long long bal = __ballot(mv[q] != 0);
        if (c == 2 * q)     mb = (uint32_t)bal;
        if (c == 2 * q + 1) mb = (uint32_t)(bal >> 32);
    }
    const bool allm = __all(mb == 0xFFFFFFFFu);
    uint32_t mh = __shfl_up(mb, 1);
    mh = (c > 0) ? (mh >> 16) : 0u;                  // halo bits = prev chunk 16..31

    // all DMA writes + mask loads complete before LDS reads (single wave: no barrier)
    asm volatile("s_waitcnt vmcnt(0)" ::: "memory");
    __builtin_amdgcn_sched_barrier(0);

    const float4* xsv = (const float4*)xs;
    const int hq = 41 * ((c > 0) ? c - 1 : 0) + 20;  // float4 idx of halo base (+80 dwords)

    // ---- halo warm-up: 15 steps in two 8-step register windows ----
    float wh[40];
#pragma unroll
    for (int k = 0; k < 10; ++k) ((float4*)wh)[k] = xsv[hq + k];
    float dp[5];
#pragma unroll
    for (int j = 0; j < 5; ++j) dp[j] = wh[j];       // raw init at step 32c-16
    if (allm) {
#pragma unroll
        for (int h = 1; h <= 7; ++h) hstep<false>(wh, 5 * h, true, dp, tr);
    } else {
#pragma unroll
        for (int h = 1; h <= 7; ++h) hstep<true>(wh, 5 * h, ((mh >> h) & 1u) != 0, dp, tr);
    }
#pragma unroll
    for (int k = 0; k < 10; ++k) ((float4*)wh)[k] = xsv[hq + 10 + k];
    if (allm) {
#pragma unroll
        for (int h = 8; h <= 15; ++h) hstep<false>(wh, 5 * (h - 8), true, dp, tr);
    } else {
#pragma unroll
        for (int h = 8; h <= 15; ++h) hstep<true>(wh, 5 * (h - 8), ((mh >> h) & 1u) != 0, dp, tr);
    }
    if (c == 0) {                                    // exact t=0 init (live l=0 masked)
#pragma unroll
        for (int j = 0; j < 5; ++j) dp[j] = xs[j] + ts[j];
    }
    float dpE[5];
#pragma unroll
    for (int j = 0; j < 5; ++j) dpE[j] = (c == 0) ? 0.0f : dp[j];

    // ---- live: 32 exact steps, bp in registers ----
    uint32_t acc[16];
#pragma unroll
    for (int bb = 0; bb < 4; ++bb) {
        float w[40];
#pragma unroll
        for (int k = 0; k < 10; ++k) ((float4*)w)[k] = xsv[41 * c + 10 * bb + k];
#pragma unroll
        for (int ll = 0; ll < 8; ++ll) {
            const int l = 8 * bb + ll;
            uint32_t pk;
            if (l == 0)    pk = lstep<true >(w, 0, (c != 0) && ((mb & 1u) != 0), dp, tr);
            else if (allm) pk = lstep<false>(w, 5 * ll, true, dp, tr);
            else           pk = lstep<true >(w, 5 * ll, ((mb >> l) & 1u) != 0, dp, tr);
            if (l & 1) acc[l >> 1] |= pk << 16;
            else       acc[l >> 1]  = pk;
        }
    }

    // ---- post-loop root map: rho = pk0 o pk1 o ... o pk31 ----
    uint32_t rho = IDENT;
#pragma unroll
    for (int l = 0; l < 32; ++l) {
        uint32_t pk = (acc[l >> 1] >> (16 * (l & 1))) & 0xFFFFu;
        rho = mcompose(rho, pk);
    }

    // exact per-chunk segment score of decoded tree (within-lane telescoping)
    float svec[5];
#pragma unroll
    for (int j = 0; j < 5; ++j) {
        int r = (rho >> (3 * j)) & 7;
        float e = dpE[0];
        e = (r == 1) ? dpE[1] : e;
        e = (r == 2) ? dpE[2] : e;
        e = (r == 3) ? dpE[3] : e;
        e = (r == 4) ? dpE[4] : e;
        svec[j] = dp[j] - e;
    }

    // ---- wave-local suffix composition over all 64 chunks ----
    uint32_t I = rho;
#pragma unroll
    for (int d = 1; d < 64; d <<= 1) {
        uint32_t oth = __shfl_down(I, d);
        uint32_t cm  = mcompose(I, oth);
        I = (c + d < 64) ? cm : I;
    }
    float best = dp[0] + te[0]; int lastv = 0;
#pragma unroll
    for (int j = 1; j < 5; ++j) {
        float s = dp[j] + te[j];
        if (s > best) { best = s; lastv = j; }
    }
    const int last = __shfl(lastv, 63);
    uint32_t M = __shfl_down(I, 1);
    M = (c < 63) ? M : IDENT;
    const int ec = (M >> (3 * last)) & 7;            // class at end of chunk c

    // ---- exact telescoped score: wave reduce ----
    {
        float v = svec[0];
        v = (ec == 1) ? svec[1] : v;
        v = (ec == 2) ? svec[2] : v;
        v = (ec == 3) ? svec[3] : v;
        v = (ec == 4) ? svec[4] : v;
        if (c == 63) v += te[last];
#pragma unroll
        for (int off = 1; off < 64; off <<= 1) v += __shfl_xor(v, off);
        if (c == 0) out[b] = v;
    }

    // ---- path decode from register bp ----
    float pv[32];
    int e = ec;
#pragma unroll
    for (int l = 31; l >= 0; --l) {
        pv[l] = (float)e;
        uint32_t p = (acc[l >> 1] >> (16 * (l & 1))) & 0xFFFFu;
        e = (p >> (3 * e)) & 7;
    }
    float* path = out + B_ + (size_t)b * T_ + c * 32;
#pragma unroll
    for (int q = 0; q < 8; ++q) {
        float4 v; v.x = pv[4*q]; v.y = pv[4*q+1]; v.z = pv[4*q+2]; v.w = pv[4*q+3];
        ((float4*)path)[q] = v;
    }
}

extern "C" void kernel_launch(void* const* d_in, const int* in_sizes, int n_in,
                              void* d_out, int out_size, void* d_ws, size_t ws_size,
                              hipStream_t stream) {
    const float* x         = (const float*)d_in[0];
    const int*   mask      = (const int*)d_in[1];
    const float* transform = (const float*)d_in[2];
    float*       out       = (float*)d_out;

    hipLaunchKernelGGL(k_all, dim3(B_), dim3(64), 0, stream,
                       x, mask, transform, out);
}

// Round 16
// 40.526 us; speedup vs baseline: 1.2503x; 1.2503x over previous
//
#include <hip/hip_runtime.h>
#include <cstdint>

#define B_ 2048
#define T_ 2048
#define TD 7
#define IDENT 0x4688u    // identity 3-bit map

// compose packed 5-slot 3-bit maps: r[j] = f[g[j]]
__device__ __forceinline__ uint32_t mcompose(uint32_t f, uint32_t g) {
    uint32_t r = 0;
#pragma unroll
    for (int j = 0; j < 5; ++j) {
        uint32_t gj = (g >> (3 * j)) & 7u;
        r |= ((f >> (3 * gj)) & 7u) << (3 * j);
    }
    return r;
}

__device__ __forceinline__ uint32_t cvtpk(float lo, float hi) {
    uint32_t r;
    asm("v_cvt_pk_bf16_f32 %0, %1, %2" : "=v"(r) : "v"(lo), "v"(hi));
    return r;
}
__device__ __forceinline__ float blo(uint32_t w) { return __uint_as_float(w << 16); }
__device__ __forceinline__ float bhi(uint32_t w) { return __uint_as_float(w & 0xFFFF0000u); }

// halo step (dp update only)
__device__ __forceinline__ void hstep5(float x0, float x1, float x2, float x3, float x4,
                                       bool mm, float (&dp)[5], const float (&tr)[5][5]) {
    const float xx[5] = {x0, x1, x2, x3, x4};
    float nd[5];
#pragma unroll
    for (int j = 0; j < 5; ++j) {
        float v = fmaxf(fmaxf(fmaxf(fmaxf(dp[0] + tr[0][j], dp[1] + tr[1][j]),
                                    dp[2] + tr[2][j]), dp[3] + tr[3][j]),
                        dp[4] + tr[4][j]);
        nd[j] = v + xx[j];
    }
#pragma unroll
    for (int j = 0; j < 5; ++j) dp[j] = mm ? nd[j] : dp[j];
}

// live step: mantissa-embedded argmax -> 3-bit packed map
__device__ __forceinline__ uint32_t vstep5(float x0, float x1, float x2, float x3, float x4,
                                           bool mm, float (&dp)[5], const float (&tr)[5][5]) {
    const float xx[5] = {x0, x1, x2, x3, x4};
    float nd[5]; uint32_t pk = 0;
#pragma unroll
    for (int j = 0; j < 5; ++j) {
        float s[5];
#pragma unroll
        for (int i = 0; i < 5; ++i) {
            float f = dp[i] + tr[i][j];
            s[i] = __uint_as_float((__float_as_uint(f) & ~7u) | (uint32_t)(7 - i));
        }
        float m = fmaxf(fmaxf(fmaxf(fmaxf(s[0], s[1]), s[2]), s[3]), s[4]);
        int a = 7 - (int)(__float_as_uint(m) & 7u);
        float v = m + xx[j];
        a = mm ? a : j;
        nd[j] = mm ? v : dp[j];
        pk |= ((uint32_t)a) << (3 * j);
    }
#pragma unroll
    for (int j = 0; j < 5; ++j) dp[j] = nd[j];
    return pk;
}

__global__ __launch_bounds__(64) void k_all(
    const float* __restrict__ x, const int* __restrict__ mask,
    const float* __restrict__ tf, float* __restrict__ out, uint32_t* __restrict__ ws)
{
    __shared__ __align__(16) uint16_t xs[10240];   // 20480 B EXACT -> 8 blocks/CU
    uint32_t* xs32 = (uint32_t*)xs;
    const int b = blockIdx.x, c = threadIdx.x;     // c = chunk (L=32)

    const float4* gx = (const float4*)(x + (size_t)b * (T_ * 5));

    // ---- stage x: coalesced float4 -> bf16 pairs -> XOR-swizzled LDS dwords ----
#pragma unroll
    for (int qo = 0; qo < 5; ++qo) {
        float4 v[8];
#pragma unroll
        for (int u = 0; u < 8; ++u) v[u] = gx[c + 64 * (8 * qo + u)];
#pragma unroll
        for (int u = 0; u < 8; ++u) {
            uint32_t e0 = 4u * (uint32_t)c + 256u * (uint32_t)(8 * qo + u);
            uint32_t co = e0 / 160u;                // exact (compiler magic)
            uint32_t k  = (e0 - 160u * co) >> 1;    // even dword offset 0..78
            uint32_t sw = (co >> 1) & 15u;
            xs32[80u * co + (k ^ sw)]        = cvtpk(v[u].x, v[u].y);
            xs32[80u * co + ((k + 1u) ^ sw)] = cvtpk(v[u].z, v[u].w);
        }
    }

    // ---- mask: per-lane own chunk (8x int4), pack 32 bits ----
    uint32_t mb = 0;
    {
        const int4* gmc = (const int4*)(mask + (size_t)b * T_ + 32 * c);
        int4 m[8];
#pragma unroll
        for (int u = 0; u < 8; ++u) m[u] = gmc[u];
#pragma unroll
        for (int u = 0; u < 8; ++u) {
            mb |= (m[u].x ? 1u : 0u) << (4 * u);
            mb |= (m[u].y ? 1u : 0u) << (4 * u + 1);
            mb |= (m[u].z ? 1u : 0u) << (4 * u + 2);
            mb |= (m[u].w ? 1u : 0u) << (4 * u + 3);
        }
    }

    float tr[5][5], ts[5], te[5];
#pragma unroll
    for (int i = 0; i < 5; ++i)
#pragma unroll
        for (int j = 0; j < 5; ++j) tr[i][j] = tf[i * TD + j];
#pragma unroll
    for (int j = 0; j < 5; ++j) ts[j] = tf[5 * TD + j];
#pragma unroll
    for (int j = 0; j < 5; ++j) te[j] = tf[j * TD + 6];

    uint32_t mh = __shfl_up(mb, 1);
    mh = (c > 0) ? (mh >> 16) : 0u;     // halo bits = prev chunk steps 16..31
    if (c == 0) mb &= ~1u;              // t==0: force identity (dp preset exactly)

    __syncthreads();                    // 1-wave block: compiles to waitcnt

    const int hc = (c > 0) ? c - 1 : 0;
    const uint32_t swl = (uint32_t)((c >> 1) & 15);
    const uint32_t swh = (uint32_t)((hc >> 1) & 15);
    const uint32_t* xl = xs32 + 80 * c;
    const uint32_t* xh = xs32 + 80 * hc;

    // ---- halo init: prev chunk o=80..84 (dwords 40,41,42) ----
    float dp[5];
    {
        uint32_t w0 = xh[40u ^ swh], w1 = xh[41u ^ swh], w2 = xh[42u ^ swh];
        dp[0] = blo(w0); dp[1] = bhi(w0); dp[2] = blo(w1); dp[3] = bhi(w1); dp[4] = blo(w2);
    }
    // halo steps h=1..14: 7 rolled iters x 2 steps
    for (int hi = 0; hi < 7; ++hi) {
        uint32_t d0 = (uint32_t)(42 + 5 * hi);
        uint32_t w0 = xh[(d0 + 0u) ^ swh], w1 = xh[(d0 + 1u) ^ swh], w2 = xh[(d0 + 2u) ^ swh];
        uint32_t w3 = xh[(d0 + 3u) ^ swh], w4 = xh[(d0 + 4u) ^ swh], w5 = xh[(d0 + 5u) ^ swh];
        bool m1 = ((mh >> (2 * hi + 1)) & 1u) != 0;
        bool m2 = ((mh >> (2 * hi + 2)) & 1u) != 0;
        hstep5(bhi(w0), blo(w1), bhi(w1), blo(w2), bhi(w2), m1, dp, tr);
        hstep5(blo(w3), bhi(w3), blo(w4), bhi(w4), blo(w5), m2, dp, tr);
    }
    {   // final halo step h=15 (o=155..159, dwords 77,78,79)
        uint32_t w0 = xh[77u ^ swh], w1 = xh[78u ^ swh], w2 = xh[79u ^ swh];
        bool m1 = ((mh >> 15) & 1u) != 0;
        hstep5(bhi(w0), blo(w1), bhi(w1), blo(w2), bhi(w2), m1, dp, tr);
    }
    if (c == 0) {   // exact t==0 init (chunk0 swizzle = 0)
        uint32_t w0 = xs32[0], w1 = xs32[1], w2 = xs32[2];
        dp[0] = blo(w0) + ts[0]; dp[1] = bhi(w0) + ts[1];
        dp[2] = blo(w1) + ts[2]; dp[3] = bhi(w1) + ts[3];
        dp[4] = blo(w2) + ts[4];
    }
    float dpE[5];
#pragma unroll
    for (int j = 0; j < 5; ++j) dpE[j] = (c == 0) ? 0.0f : dp[j];

    // ---- live: rolled 16 iters x 2 steps; pk pair -> global ws (coalesced) ----
    uint32_t rho = IDENT;
    uint32_t* wrow = ws + ((size_t)b << 10) + c;     // [(b*16+it)*64 + c]
    for (int it = 0; it < 16; ++it) {
        uint32_t d0 = (uint32_t)(5 * it);
        uint32_t w0 = xl[(d0 + 0u) ^ swl], w1 = xl[(d0 + 1u) ^ swl], w2 = xl[(d0 + 2u) ^ swl];
        uint32_t w3 = xl[(d0 + 3u) ^ swl], w4 = xl[(d0 + 4u) ^ swl];
        bool mA = ((mb >> (2 * it)) & 1u) != 0;
        bool mB = ((mb >> (2 * it + 1)) & 1u) != 0;
        uint32_t pkA = vstep5(blo(w0), bhi(w0), blo(w1), bhi(w1), blo(w2), mA, dp, tr);
        rho = mcompose(rho, pkA);
        uint32_t pkB = vstep5(bhi(w2), blo(w3), bhi(w3), blo(w4), bhi(w4), mB, dp, tr);
        rho = mcompose(rho, pkB);
        wrow[it * 64] = pkA | (pkB << 16);
    }

    // ---- exact per-chunk segment score (within-lane telescoping) ----
    float svec[5];
#pragma unroll
    for (int j = 0; j < 5; ++j) {
        int r = (rho >> (3 * j)) & 7;
        float e = dpE[0];
        e = (r == 1) ? dpE[1] : e;
        e = (r == 2) ? dpE[2] : e;
        e = (r == 3) ? dpE[3] : e;
        e = (r == 4) ? dpE[4] : e;
        svec[j] = dp[j] - e;
    }

    // ---- wave suffix composition over 64 chunks ----
    uint32_t I = rho;
#pragma unroll
    for (int d = 1; d < 64; d <<= 1) {
        uint32_t oth = __shfl_down(I, d);
        uint32_t cm  = mcompose(I, oth);
        I = (c + d < 64) ? cm : I;
    }
    float best = dp[0] + te[0]; int lastv = 0;
#pragma unroll
    for (int j = 1; j < 5; ++j) {
        float s = dp[j] + te[j];
        if (s > best) { best = s; lastv = j; }
    }
    const int last = __shfl(lastv, 63);
    uint32_t M = __shfl_down(I, 1);
    M = (c < 63) ? M : IDENT;
    const int ec = (int)((M >> (3 * last)) & 7u);

    // ---- exact telescoped score: wave reduce ----
    {
        float v = svec[0];
        v = (ec == 1) ? svec[1] : v;
        v = (ec == 2) ? svec[2] : v;
        v = (ec == 3) ? svec[3] : v;
        v = (ec == 4) ? svec[4] : v;
        if (c == 63) v += te[last];
#pragma unroll
        for (int off = 1; off < 64; off <<= 1) v += __shfl_xor(v, off);
        if (c == 0) out[b] = v;
    }

    // ---- path decode: 4 iters x (4 ws reads + 8 steps + 2 float4 stores) ----
    const uint32_t* rrow = ws + ((size_t)b << 10) + c;
    float* path = out + B_ + (size_t)b * T_ + 32 * c;
    int e = ec;
    for (int dd = 3; dd >= 0; --dd) {
        uint32_t q0 = rrow[(4 * dd + 0) * 64], q1 = rrow[(4 * dd + 1) * 64];
        uint32_t q2 = rrow[(4 * dd + 2) * 64], q3 = rrow[(4 * dd + 3) * 64];
        float pv[8];
        {
            uint32_t pB = q3 >> 16, pA = q3 & 0xFFFFu;
            pv[7] = (float)e; e = (int)((pB >> (3 * e)) & 7u);
            pv[6] = (float)e; e = (int)((pA >> (3 * e)) & 7u);
        }
        {
            uint32_t pB = q2 >> 16, pA = q2 & 0xFFFFu;
            pv[5] = (float)e; e = (int)((pB >> (3 * e)) & 7u);
            pv[4] = (float)e; e = (int)((pA >> (3 * e)) & 7u);
        }
        {
            uint32_t pB = q1 >> 16, pA = q1 & 0xFFFFu;
            pv[3] = (float)e; e = (int)((pB >> (3 * e)) & 7u);
            pv[2] = (float)e; e = (int)((pA >> (3 * e)) & 7u);
        }
        {
            uint32_t pB = q0 >> 16, pA = q0 & 0xFFFFu;
            pv[1] = (float)e; e = (int)((pB >> (3 * e)) & 7u);
            pv[0] = (float)e; e = (int)((pA >> (3 * e)) & 7u);
        }
        float4 s0; s0.x = pv[0]; s0.y = pv[1]; s0.z = pv[2]; s0.w = pv[3];
        float4 s1; s1.x = pv[4]; s1.y = pv[5]; s1.z = pv[6]; s1.w = pv[7];
        ((float4*)path)[2 * dd]     = s0;
        ((float4*)path)[2 * dd + 1] = s1;
    }
}

extern "C" void kernel_launch(void* const* d_in, const int* in_sizes, int n_in,
                              void* d_out, int out_size, void* d_ws, size_t ws_size,
                              hipStream_t stream) {
    const float* x         = (const float*)d_in[0];
    const int*   mask      = (const int*)d_in[1];
    const float* transform = (const float*)d_in[2];
    float*       out       = (float*)d_out;
    uint32_t*    ws        = (uint32_t*)d_ws;       // 8 MiB backpointer buffer

    hipLaunchKernelGGL(k_all, dim3(B_), dim3(64), 0, stream,
                       x, mask, transform, out, ws);
}